// Round 1
// baseline (196.830 us; speedup 1.0000x reference)
//
#include <hip/hip_runtime.h>

#define HW      147456           // 384*384
#define NC      5
#define NT      40               // 4*10
#define NPIX    (NT * HW)        // 5,898,240
#define NGROUP  (NPIX / 4)       // 1,474,560 float4 groups
#define SMOOTH  1e-5f

__global__ void dice_init_ws(float* __restrict__ ws) {
    if (threadIdx.x < 16) ws[threadIdx.x] = 0.0f;
}

__global__ __launch_bounds__(256) void dice_main(const float* __restrict__ inp,
                                                 const float* __restrict__ tgt,
                                                 float* __restrict__ ws) {
    float sumx[NC]  = {0.f, 0.f, 0.f, 0.f, 0.f};
    float inter[NC] = {0.f, 0.f, 0.f, 0.f, 0.f};
    float cnt[NC]   = {0.f, 0.f, 0.f, 0.f, 0.f};

    const int tid    = blockIdx.x * 256 + threadIdx.x;
    const int stride = gridDim.x * 256;

    for (int g = tid; g < NGROUP; g += stride) {
        const int p  = g << 2;            // pixel index; also the flat target index
        const int nt = p / HW;            // magic-mul division by 147456
        const int hw = p - nt * HW;

        const float4 t4 = reinterpret_cast<const float4*>(tgt)[g];
        const int c0 = (t4.x >= 0.25f) + (t4.x >= 0.375f) + (t4.x >= 0.5f) + (t4.x >= 0.625f);
        const int c1 = (t4.y >= 0.25f) + (t4.y >= 0.375f) + (t4.y >= 0.5f) + (t4.y >= 0.625f);
        const int c2 = (t4.z >= 0.25f) + (t4.z >= 0.375f) + (t4.z >= 0.5f) + (t4.z >= 0.625f);
        const int c3 = (t4.w >= 0.25f) + (t4.w >= 0.375f) + (t4.w >= 0.5f) + (t4.w >= 0.625f);

        const float* base = inp + (size_t)nt * (size_t)(NC * HW) + (size_t)hw;
        #pragma unroll
        for (int c = 0; c < NC; ++c) {
            const float4 x4 = *reinterpret_cast<const float4*>(base + (size_t)c * HW);
            sumx[c] += (x4.x + x4.y) + (x4.z + x4.w);
            float iv = 0.f;
            if (c0 == c) iv += x4.x;
            if (c1 == c) iv += x4.y;
            if (c2 == c) iv += x4.z;
            if (c3 == c) iv += x4.w;
            inter[c] += iv;
            cnt[c]   += (float)((c0 == c) + (c1 == c) + (c2 == c) + (c3 == c));
        }
    }

    // pack 15 accumulators: [0..4]=sumx, [5..9]=inter, [10..14]=cnt
    float v[15];
    #pragma unroll
    for (int c = 0; c < NC; ++c) { v[c] = sumx[c]; v[5 + c] = inter[c]; v[10 + c] = cnt[c]; }

    // wave-64 butterfly reduce
    #pragma unroll
    for (int j = 0; j < 15; ++j) {
        #pragma unroll
        for (int off = 32; off > 0; off >>= 1)
            v[j] += __shfl_down(v[j], off, 64);
    }

    __shared__ float part[4][15];
    const int lane = threadIdx.x & 63;
    const int wv   = threadIdx.x >> 6;
    if (lane == 0) {
        #pragma unroll
        for (int j = 0; j < 15; ++j) part[wv][j] = v[j];
    }
    __syncthreads();
    if (threadIdx.x < 15) {
        const float s = part[0][threadIdx.x] + part[1][threadIdx.x] +
                        part[2][threadIdx.x] + part[3][threadIdx.x];
        atomicAdd(&ws[threadIdx.x], s);
    }
}

__global__ void dice_final(const float* __restrict__ ws,
                           const float* __restrict__ w,
                           float* __restrict__ out) {
    if (threadIdx.x == 0) {
        float loss = 0.f;
        #pragma unroll
        for (int c = 0; c < NC; ++c) {
            const float inter = ws[5 + c];
            const float denom = ws[c] + ws[10 + c];
            loss += w[c] * (1.f - (2.f * inter + SMOOTH) / (denom + SMOOTH));
        }
        out[0] = loss;
    }
}

extern "C" void kernel_launch(void* const* d_in, const int* in_sizes, int n_in,
                              void* d_out, int out_size, void* d_ws, size_t ws_size,
                              hipStream_t stream) {
    const float* inp = (const float*)d_in[0];
    const float* tgt = (const float*)d_in[1];
    const float* wgt = (const float*)d_in[2];
    float* out = (float*)d_out;
    float* ws  = (float*)d_ws;

    dice_init_ws<<<1, 64, 0, stream>>>(ws);
    // 1440 blocks * 256 thr = 368,640 threads -> 4 float4-groups each
    dice_main<<<1440, 256, 0, stream>>>(inp, tgt, ws);
    dice_final<<<1, 64, 0, stream>>>(ws, wgt, out);
}